// Round 3
// baseline (703.228 us; speedup 1.0000x reference)
//
#include <hip/hip_runtime.h>
#include <hip/hip_bf16.h>
#include <stdint.h>

#define N_NODES 100000
#define N_EDGES 1600000
#define N_BUCKETS 782            // ceil(100000 / 128)

// ---- workspace layout (bytes) ----
static const size_t OFF_H    = 0;            // h bf16: 100000*128*2 = 25,600,000
static const size_t OFF_SDEG = 25600000;     // int 400,000
static const size_t OFF_RDEG = 26000000;     // int 400,000 (contiguous w/ sdeg for memset)
static const size_t OFF_ROWP = 26400000;     // int 400,004
static const size_t OFF_BSUM = 26800016;     // int 1,024
static const size_t OFF_BCUR = 26801040;     // int 3,128 (782 bucket cursors)
static const size_t OFF_EBUF = 26804176;     // uint 6,400,000 -> total ~33.2 MB
                                             // (scatter1 packed edges; scatter2 rewrites
                                             //  in place to receiver-sorted sender ids)

using short8 = __attribute__((ext_vector_type(8))) short;
using f32x4  = __attribute__((ext_vector_type(4))) float;

// fp32 -> bf16 bits, round-to-nearest-even (finite inputs)
static __device__ __forceinline__ short f2bf(float f) {
    uint32_t u = __float_as_uint(f);
    uint32_t r = (u + 0x7fffu + ((u >> 16) & 1u)) >> 16;
    return (short)r;
}

// 1) degree counting
__global__ __launch_bounds__(256) void deg_kernel(const int* __restrict__ snd,
                                                  const int* __restrict__ rcv,
                                                  int* __restrict__ sdeg,
                                                  int* __restrict__ rdeg) {
    int e = blockIdx.x * 256 + threadIdx.x;
    if (e < N_EDGES) {
        atomicAdd(&sdeg[snd[e]], 1);
        atomicAdd(&rdeg[rcv[e]], 1);
    }
}

// 2) block-level exclusive scan of rdeg -> row_ptr (partial) + block sums
__global__ __launch_bounds__(512) void scan1_kernel(const int* __restrict__ rdeg,
                                                    int* __restrict__ exscan,
                                                    int* __restrict__ bsums) {
    __shared__ int s[512];
    int t = threadIdx.x;
    int i = blockIdx.x * 512 + t;
    int v = (i < N_NODES) ? rdeg[i] : 0;
    s[t] = v;
    __syncthreads();
    #pragma unroll
    for (int off = 1; off < 512; off <<= 1) {
        int tv = (t >= off) ? s[t - off] : 0;
        __syncthreads();
        s[t] += tv;
        __syncthreads();
    }
    if (i < N_NODES) exscan[i] = s[t] - v;
    if (t == 511) bsums[blockIdx.x] = s[511];
}

// 3) scan the 196 block sums
__global__ __launch_bounds__(256) void scan2_kernel(int* __restrict__ bsums) {
    __shared__ int s[256];
    int t = threadIdx.x;
    int v = (t < 196) ? bsums[t] : 0;
    s[t] = v;
    __syncthreads();
    #pragma unroll
    for (int off = 1; off < 256; off <<= 1) {
        int tv = (t >= off) ? s[t - off] : 0;
        __syncthreads();
        s[t] += tv;
        __syncthreads();
    }
    if (t < 196) bsums[t] = s[t] - v;
}

// 4) final row_ptr; init per-bucket cursors at bucket boundaries
__global__ __launch_bounds__(512) void scan3_kernel(int* __restrict__ row_ptr,
                                                    const int* __restrict__ bsums,
                                                    int* __restrict__ bcursor) {
    int i = blockIdx.x * 512 + threadIdx.x;
    if (i < N_NODES) {
        int r = row_ptr[i] + bsums[blockIdx.x];
        row_ptr[i] = r;
        if ((i & 127) == 0) bcursor[i >> 7] = r;
    } else if (i == N_NODES) {
        row_ptr[N_NODES] = N_EDGES;
    }
}

// 5) MFMA GEMM: h[n][d] = bf16((x[n]·W[:,d] + bias[d]) * rsqrt(max(sdeg[n],1)))
__global__ __launch_bounds__(256) void gemm_mfma_kernel(const float* __restrict__ x,
                                                        const float* __restrict__ W,
                                                        const float* __restrict__ bias,
                                                        const int* __restrict__ sdeg,
                                                        short* __restrict__ h) {
    __shared__ __align__(16) short Wl[32 * 64 * 8];   // [frag s*8+c][lane][j]
    __shared__ float bias_s[128];

    const int t = threadIdx.x;
    const int lane = t & 63;
    const int wv = t >> 6;
    const int quad = lane >> 4;
    const int mcol = lane & 15;

    #pragma unroll
    for (int i = 0; i < 8; i++) {
        int f = wv + 4 * i;
        int s = f >> 3;
        int c = f & 7;
        int krow = s * 32 + quad * 8;
        int ncol = c * 16 + mcol;
        short8 wf;
        #pragma unroll
        for (int j = 0; j < 8; j++)
            wf[j] = f2bf(W[(krow + j) * 128 + ncol]);
        *(short8*)&Wl[(f * 64 + lane) * 8] = wf;
    }
    if (t < 128) bias_s[t] = bias[t];

    const int node0 = blockIdx.x * 128 + wv * 32;
    short8 afrag[2][4];
    #pragma unroll
    for (int mf = 0; mf < 2; mf++) {
        int node = node0 + mf * 16 + mcol;
        bool ok = node < N_NODES;
        const float* xr = x + (size_t)(ok ? node : 0) * 128;
        #pragma unroll
        for (int s = 0; s < 4; s++) {
            int k0 = s * 32 + quad * 8;
            f32x4 v0 = ok ? *(const f32x4*)(xr + k0)     : f32x4{0.f,0.f,0.f,0.f};
            f32x4 v1 = ok ? *(const f32x4*)(xr + k0 + 4) : f32x4{0.f,0.f,0.f,0.f};
            short8 af;
            #pragma unroll
            for (int j = 0; j < 4; j++) {
                af[j]     = f2bf(v0[j]);
                af[4 + j] = f2bf(v1[j]);
            }
            afrag[mf][s] = af;
        }
    }

    __syncthreads();

    f32x4 acc[2][8];
    #pragma unroll
    for (int mf = 0; mf < 2; mf++)
        #pragma unroll
        for (int c = 0; c < 8; c++)
            acc[mf][c] = f32x4{0.f, 0.f, 0.f, 0.f};

    #pragma unroll
    for (int s = 0; s < 4; s++) {
        #pragma unroll
        for (int c = 0; c < 8; c++) {
            short8 bfrag = *(const short8*)&Wl[((s * 8 + c) * 64 + lane) * 8];
            acc[0][c] = __builtin_amdgcn_mfma_f32_16x16x32_bf16(afrag[0][s], bfrag, acc[0][c], 0, 0, 0);
            acc[1][c] = __builtin_amdgcn_mfma_f32_16x16x32_bf16(afrag[1][s], bfrag, acc[1][c], 0, 0, 0);
        }
    }

    float rsv[2][4];
    #pragma unroll
    for (int mf = 0; mf < 2; mf++)
        #pragma unroll
        for (int r = 0; r < 4; r++) {
            int nd = node0 + mf * 16 + quad * 4 + r;
            float dg = (nd < N_NODES) ? (float)sdeg[nd] : 1.f;
            rsv[mf][r] = rsqrtf(fmaxf(dg, 1.f));
        }

    #pragma unroll
    for (int mf = 0; mf < 2; mf++)
        #pragma unroll
        for (int c = 0; c < 8; c++) {
            float bval = bias_s[c * 16 + mcol];
            #pragma unroll
            for (int r = 0; r < 4; r++) {
                int nd = node0 + mf * 16 + quad * 4 + r;
                if (nd < N_NODES)
                    h[(size_t)nd * 128 + c * 16 + mcol] =
                        f2bf((acc[mf][c][r] + bval) * rsv[mf][r]);
            }
        }
}

// 6a) coarse bucket scatter: pack (snd, rcv&127) and append to the receiver's
//     bucket (rcv>>7). Only ~782 active write lines -> lines fill in L2.
__global__ __launch_bounds__(256) void scatter1_kernel(const int* __restrict__ snd,
                                                       const int* __restrict__ rcv,
                                                       int* __restrict__ bcursor,
                                                       uint32_t* __restrict__ ebuf) {
    int e = blockIdx.x * 256 + threadIdx.x;
    if (e < N_EDGES) {
        int r = rcv[e];
        int s = snd[e];
        int pos = atomicAdd(&bcursor[r >> 7], 1);
        ebuf[pos] = ((uint32_t)s << 7) | (uint32_t)(r & 127);
    }
}

// 6b) per-bucket sort: one block per bucket. Coalesced read of the bucket's
//     packed edges, LDS-cursor permutation into LDS, coalesced in-place
//     write-back of receiver-sorted sender ids.
__global__ __launch_bounds__(256) void scatter2_kernel(const int* __restrict__ row_ptr,
                                                       uint32_t* __restrict__ ebuf) {
    __shared__ int cursor_l[128];
    __shared__ uint32_t perm[8192];   // 32 KB; bucket size ~2048 (binomial, sigma~45)

    int b = blockIdx.x;
    int t = threadIdx.x;
    int nbase = b * 128;
    int base = row_ptr[nbase];
    int end_node = nbase + 128;
    if (end_node > N_NODES) end_node = N_NODES;
    int end = row_ptr[end_node];
    int size = end - base;

    if (t < 128) {
        int n = nbase + t;
        cursor_l[t] = (n < N_NODES ? row_ptr[n] : end) - base;
    }
    __syncthreads();

    for (int i = t; i < size; i += 256) {
        uint32_t v = ebuf[base + i];
        int r = (int)(v & 127u);
        int pos = atomicAdd(&cursor_l[r], 1);
        perm[pos] = v >> 7;
    }
    __syncthreads();

    for (int i = t; i < size; i += 256)
        ebuf[base + i] = perm[i];
}

// 7) gather: one wave per node; degree from row_ptr; 4-wide edge unroll
__global__ __launch_bounds__(256) void gather_kernel(const uint32_t* __restrict__ h2,
                                                     const int* __restrict__ row_ptr,
                                                     const uint32_t* __restrict__ esrc,
                                                     float2* __restrict__ out2) {
    int node = blockIdx.x * 4 + (threadIdx.x >> 6);
    int lane = threadIdx.x & 63;
    int b = row_ptr[node];
    int e = row_ptr[node + 1];
    float a0 = 0.f, a1 = 0.f;
    int i = b;
    for (; i + 4 <= e; i += 4) {
        uint32_t s0 = esrc[i + 0], s1 = esrc[i + 1], s2 = esrc[i + 2], s3 = esrc[i + 3];
        uint32_t v0 = h2[(size_t)s0 * 64 + lane];
        uint32_t v1 = h2[(size_t)s1 * 64 + lane];
        uint32_t v2 = h2[(size_t)s2 * 64 + lane];
        uint32_t v3 = h2[(size_t)s3 * 64 + lane];
        a0 += __uint_as_float(v0 << 16) + __uint_as_float(v1 << 16)
            + __uint_as_float(v2 << 16) + __uint_as_float(v3 << 16);
        a1 += __uint_as_float(v0 & 0xffff0000u) + __uint_as_float(v1 & 0xffff0000u)
            + __uint_as_float(v2 & 0xffff0000u) + __uint_as_float(v3 & 0xffff0000u);
    }
    for (; i < e; i++) {
        uint32_t s = esrc[i];
        uint32_t v = h2[(size_t)s * 64 + lane];
        a0 += __uint_as_float(v << 16);
        a1 += __uint_as_float(v & 0xffff0000u);
    }
    float rs = rsqrtf(fmaxf((float)(e - b), 1.f));
    out2[(size_t)node * 64 + lane] = make_float2(a0 * rs, a1 * rs);
}

extern "C" void kernel_launch(void* const* d_in, const int* in_sizes, int n_in,
                              void* d_out, int out_size, void* d_ws, size_t ws_size,
                              hipStream_t stream) {
    const float* x    = (const float*)d_in[0];
    const int*   snd  = (const int*)d_in[1];
    const int*   rcv  = (const int*)d_in[2];
    const float* W    = (const float*)d_in[4];
    const float* bias = (const float*)d_in[5];

    char* ws = (char*)d_ws;
    short* h      = (short*)(ws + OFF_H);
    int* sdeg     = (int*)(ws + OFF_SDEG);
    int* rdeg     = (int*)(ws + OFF_RDEG);
    int* rowp     = (int*)(ws + OFF_ROWP);
    int* bsum     = (int*)(ws + OFF_BSUM);
    int* bcur     = (int*)(ws + OFF_BCUR);
    uint32_t* ebuf = (uint32_t*)(ws + OFF_EBUF);

    hipMemsetAsync(ws + OFF_SDEG, 0, 2 * N_NODES * sizeof(int), stream);

    deg_kernel     <<<(N_EDGES + 255) / 256, 256, 0, stream>>>(snd, rcv, sdeg, rdeg);
    scan1_kernel   <<<196, 512, 0, stream>>>(rdeg, rowp, bsum);
    scan2_kernel   <<<1, 256, 0, stream>>>(bsum);
    scan3_kernel   <<<196, 512, 0, stream>>>(rowp, bsum, bcur);
    gemm_mfma_kernel<<<(N_NODES + 127) / 128, 256, 0, stream>>>(x, W, bias, sdeg, h);
    scatter1_kernel<<<(N_EDGES + 255) / 256, 256, 0, stream>>>(snd, rcv, bcur, ebuf);
    scatter2_kernel<<<N_BUCKETS, 256, 0, stream>>>(rowp, ebuf);
    gather_kernel  <<<N_NODES / 4, 256, 0, stream>>>((const uint32_t*)h, rowp, ebuf, (float2*)d_out);
}

// Round 4
// 361.525 us; speedup vs baseline: 1.9452x; 1.9452x over previous
//
#include <hip/hip_runtime.h>
#include <hip/hip_bf16.h>
#include <stdint.h>

#define N_NODES 100000
#define N_EDGES 1600000
#define TILE 8192
#define S1_BLOCKS ((N_EDGES + TILE - 1) / TILE)       // 196
#define N_BUCKETS 196                                  // ceil(100000/512), bucket = rcv>>9

// ---- workspace layout (bytes) ----
static const size_t OFF_H    = 0;            // h bf16: 100000*128*2 = 25,600,000
static const size_t OFF_SDEG = 25600000;     // int 400,000
static const size_t OFF_RDEG = 26000000;     // int 400,000 (contiguous w/ sdeg for memset)
static const size_t OFF_ROWP = 26400000;     // int 400,004
static const size_t OFF_BSUM = 26800016;     // int 1,024
static const size_t OFF_BCUR = 26801040;     // int 1,024 (196 bucket cursors)
static const size_t OFF_EBUF = 26802064;     // uint 6,400,000 -> total ~33.2 MB

using short8 = __attribute__((ext_vector_type(8))) short;
using f32x4  = __attribute__((ext_vector_type(4))) float;

// fp32 -> bf16 bits, round-to-nearest-even (finite inputs)
static __device__ __forceinline__ short f2bf(float f) {
    uint32_t u = __float_as_uint(f);
    uint32_t r = (u + 0x7fffu + ((u >> 16) & 1u)) >> 16;
    return (short)r;
}

// 1) degree counting
__global__ __launch_bounds__(256) void deg_kernel(const int* __restrict__ snd,
                                                  const int* __restrict__ rcv,
                                                  int* __restrict__ sdeg,
                                                  int* __restrict__ rdeg) {
    int e = blockIdx.x * 256 + threadIdx.x;
    if (e < N_EDGES) {
        atomicAdd(&sdeg[snd[e]], 1);
        atomicAdd(&rdeg[rcv[e]], 1);
    }
}

// 2) block-level exclusive scan of rdeg -> row_ptr (partial) + block sums
__global__ __launch_bounds__(512) void scan1_kernel(const int* __restrict__ rdeg,
                                                    int* __restrict__ exscan,
                                                    int* __restrict__ bsums) {
    __shared__ int s[512];
    int t = threadIdx.x;
    int i = blockIdx.x * 512 + t;
    int v = (i < N_NODES) ? rdeg[i] : 0;
    s[t] = v;
    __syncthreads();
    #pragma unroll
    for (int off = 1; off < 512; off <<= 1) {
        int tv = (t >= off) ? s[t - off] : 0;
        __syncthreads();
        s[t] += tv;
        __syncthreads();
    }
    if (i < N_NODES) exscan[i] = s[t] - v;
    if (t == 511) bsums[blockIdx.x] = s[511];
}

// 3) scan the 196 block sums
__global__ __launch_bounds__(256) void scan2_kernel(int* __restrict__ bsums) {
    __shared__ int s[256];
    int t = threadIdx.x;
    int v = (t < 196) ? bsums[t] : 0;
    s[t] = v;
    __syncthreads();
    #pragma unroll
    for (int off = 1; off < 256; off <<= 1) {
        int tv = (t >= off) ? s[t - off] : 0;
        __syncthreads();
        s[t] += tv;
        __syncthreads();
    }
    if (t < 196) bsums[t] = s[t] - v;
}

// 4) final row_ptr; init per-bucket global cursors at 512-node boundaries
__global__ __launch_bounds__(512) void scan3_kernel(int* __restrict__ row_ptr,
                                                    const int* __restrict__ bsums,
                                                    int* __restrict__ bcursor) {
    int i = blockIdx.x * 512 + threadIdx.x;
    if (i < N_NODES) {
        int r = row_ptr[i] + bsums[blockIdx.x];
        row_ptr[i] = r;
        if ((i & 511) == 0) bcursor[i >> 9] = r;
    } else if (i == N_NODES) {
        row_ptr[N_NODES] = N_EDGES;
    }
}

// 5) MFMA GEMM: h[n][d] = bf16((x[n]·W[:,d] + bias[d]) * rsqrt(max(sdeg[n],1)))
__global__ __launch_bounds__(256) void gemm_mfma_kernel(const float* __restrict__ x,
                                                        const float* __restrict__ W,
                                                        const float* __restrict__ bias,
                                                        const int* __restrict__ sdeg,
                                                        short* __restrict__ h) {
    __shared__ __align__(16) short Wl[32 * 64 * 8];   // [frag s*8+c][lane][j]
    __shared__ float bias_s[128];

    const int t = threadIdx.x;
    const int lane = t & 63;
    const int wv = t >> 6;
    const int quad = lane >> 4;
    const int mcol = lane & 15;

    #pragma unroll
    for (int i = 0; i < 8; i++) {
        int f = wv + 4 * i;
        int s = f >> 3;
        int c = f & 7;
        int krow = s * 32 + quad * 8;
        int ncol = c * 16 + mcol;
        short8 wf;
        #pragma unroll
        for (int j = 0; j < 8; j++)
            wf[j] = f2bf(W[(krow + j) * 128 + ncol]);
        *(short8*)&Wl[(f * 64 + lane) * 8] = wf;
    }
    if (t < 128) bias_s[t] = bias[t];

    const int node0 = blockIdx.x * 128 + wv * 32;
    short8 afrag[2][4];
    #pragma unroll
    for (int mf = 0; mf < 2; mf++) {
        int node = node0 + mf * 16 + mcol;
        bool ok = node < N_NODES;
        const float* xr = x + (size_t)(ok ? node : 0) * 128;
        #pragma unroll
        for (int s = 0; s < 4; s++) {
            int k0 = s * 32 + quad * 8;
            f32x4 v0 = ok ? *(const f32x4*)(xr + k0)     : f32x4{0.f,0.f,0.f,0.f};
            f32x4 v1 = ok ? *(const f32x4*)(xr + k0 + 4) : f32x4{0.f,0.f,0.f,0.f};
            short8 af;
            #pragma unroll
            for (int j = 0; j < 4; j++) {
                af[j]     = f2bf(v0[j]);
                af[4 + j] = f2bf(v1[j]);
            }
            afrag[mf][s] = af;
        }
    }

    __syncthreads();

    f32x4 acc[2][8];
    #pragma unroll
    for (int mf = 0; mf < 2; mf++)
        #pragma unroll
        for (int c = 0; c < 8; c++)
            acc[mf][c] = f32x4{0.f, 0.f, 0.f, 0.f};

    #pragma unroll
    for (int s = 0; s < 4; s++) {
        #pragma unroll
        for (int c = 0; c < 8; c++) {
            short8 bfrag = *(const short8*)&Wl[((s * 8 + c) * 64 + lane) * 8];
            acc[0][c] = __builtin_amdgcn_mfma_f32_16x16x32_bf16(afrag[0][s], bfrag, acc[0][c], 0, 0, 0);
            acc[1][c] = __builtin_amdgcn_mfma_f32_16x16x32_bf16(afrag[1][s], bfrag, acc[1][c], 0, 0, 0);
        }
    }

    float rsv[2][4];
    #pragma unroll
    for (int mf = 0; mf < 2; mf++)
        #pragma unroll
        for (int r = 0; r < 4; r++) {
            int nd = node0 + mf * 16 + quad * 4 + r;
            float dg = (nd < N_NODES) ? (float)sdeg[nd] : 1.f;
            rsv[mf][r] = rsqrtf(fmaxf(dg, 1.f));
        }

    #pragma unroll
    for (int mf = 0; mf < 2; mf++)
        #pragma unroll
        for (int c = 0; c < 8; c++) {
            float bval = bias_s[c * 16 + mcol];
            #pragma unroll
            for (int r = 0; r < 4; r++) {
                int nd = node0 + mf * 16 + quad * 4 + r;
                if (nd < N_NODES)
                    h[(size_t)nd * 128 + c * 16 + mcol] =
                        f2bf((acc[mf][c][r] + bval) * rsv[mf][r]);
            }
        }
}

// 6a) LDS-staged coarse binning. Per block: 8192-edge tile -> LDS histogram over
//     256 buckets (rcv>>9) -> LDS scan -> one global atomicAdd per non-empty
//     bucket to reserve space -> re-bin into 32KB LDS stage -> stream out with
//     consecutive-lane writes (contiguous per-bucket chunks; no random 4B stores).
__global__ __launch_bounds__(256) void scatter1_kernel(const int* __restrict__ snd,
                                                       const int* __restrict__ rcv,
                                                       int* __restrict__ gcur,
                                                       uint32_t* __restrict__ ebuf) {
    __shared__ int hist[256];
    __shared__ int coff[256];      // frozen exclusive scan of hist
    __shared__ int ccur[256];      // scan temp, then working cursor
    __shared__ int gbase[256];     // global base minus coff (target = gbase[b]+pos)
    __shared__ uint32_t stage[TILE];   // 32 KB

    const int t = threadIdx.x;
    const int base = blockIdx.x * TILE;

    // load tile to registers (coalesced)
    uint32_t ss[32], rs[32];
    #pragma unroll
    for (int j = 0; j < 32; j++) {
        int idx = base + j * 256 + t;
        bool ok = idx < N_EDGES;
        ss[j] = ok ? (uint32_t)snd[idx] : 0u;
        rs[j] = ok ? (uint32_t)rcv[idx] : 0xffffffffu;   // sentinel = invalid
    }

    hist[t] = 0;
    __syncthreads();
    #pragma unroll
    for (int j = 0; j < 32; j++)
        if (rs[j] != 0xffffffffu) atomicAdd(&hist[rs[j] >> 9], 1);
    __syncthreads();

    // Hillis-Steele inclusive scan in ccur
    int v = hist[t];
    ccur[t] = v;
    __syncthreads();
    #pragma unroll
    for (int off = 1; off < 256; off <<= 1) {
        int tv = (t >= off) ? ccur[t - off] : 0;
        __syncthreads();
        ccur[t] += tv;
        __syncthreads();
    }
    int excl = ccur[t] - v;
    coff[t] = excl;
    int gb = 0;
    if (v > 0) gb = atomicAdd(&gcur[t], v);    // t < 196 for non-empty buckets
    gbase[t] = gb - excl;
    __syncthreads();
    ccur[t] = excl;                            // working cursor for pass 2
    __syncthreads();

    // pass 2: bin into LDS stage, packed (snd<<9 | rcv&511)
    #pragma unroll
    for (int j = 0; j < 32; j++) {
        uint32_t r = rs[j];
        if (r != 0xffffffffu) {
            int pos = atomicAdd(&ccur[r >> 9], 1);
            stage[pos] = (ss[j] << 9) | (r & 511u);
        }
    }
    __syncthreads();

    // stream out: consecutive staged positions -> consecutive global addresses
    // within each bucket chunk. Binary search coff for the owning bucket.
    int total = coff[255] + hist[255];
    for (int i = t; i < total; i += 256) {
        uint32_t pv = stage[i];
        int lo = 0;
        #pragma unroll
        for (int step = 128; step; step >>= 1)
            if (lo + step < 256 && coff[lo + step] <= i) lo += step;
        ebuf[gbase[lo] + i] = pv;
    }
}

// 6b) per-bucket sort: one block per 512-node bucket. Coalesced read, LDS-cursor
//     permute (cursors from row_ptr), coalesced in-place write-back of sender ids.
__global__ __launch_bounds__(256) void scatter2_kernel(const int* __restrict__ row_ptr,
                                                       uint32_t* __restrict__ ebuf) {
    __shared__ int cursor_l[512];
    __shared__ uint32_t perm[9216];   // 36 KB; bucket avg 8192, sigma~90

    int b = blockIdx.x;
    int t = threadIdx.x;
    int nbase = b << 9;
    int base = row_ptr[nbase];
    int end_node = nbase + 512;
    if (end_node > N_NODES) end_node = N_NODES;
    int end = row_ptr[end_node];
    int size = end - base;

    for (int i = t; i < 512; i += 256) {
        int n = nbase + i;
        cursor_l[i] = (n < N_NODES ? row_ptr[n] : end) - base;
    }
    __syncthreads();

    for (int i = t; i < size; i += 256) {
        uint32_t v = ebuf[base + i];
        int pos = atomicAdd(&cursor_l[v & 511u], 1);
        perm[pos] = v >> 9;
    }
    __syncthreads();

    for (int i = t; i < size; i += 256)
        ebuf[base + i] = perm[i];
}

// 7) gather: one wave per node; degree from row_ptr; 4-wide edge unroll
__global__ __launch_bounds__(256) void gather_kernel(const uint32_t* __restrict__ h2,
                                                     const int* __restrict__ row_ptr,
                                                     const uint32_t* __restrict__ esrc,
                                                     float2* __restrict__ out2) {
    int node = blockIdx.x * 4 + (threadIdx.x >> 6);
    int lane = threadIdx.x & 63;
    int b = row_ptr[node];
    int e = row_ptr[node + 1];
    float a0 = 0.f, a1 = 0.f;
    int i = b;
    for (; i + 4 <= e; i += 4) {
        uint32_t s0 = esrc[i + 0], s1 = esrc[i + 1], s2 = esrc[i + 2], s3 = esrc[i + 3];
        uint32_t v0 = h2[(size_t)s0 * 64 + lane];
        uint32_t v1 = h2[(size_t)s1 * 64 + lane];
        uint32_t v2 = h2[(size_t)s2 * 64 + lane];
        uint32_t v3 = h2[(size_t)s3 * 64 + lane];
        a0 += __uint_as_float(v0 << 16) + __uint_as_float(v1 << 16)
            + __uint_as_float(v2 << 16) + __uint_as_float(v3 << 16);
        a1 += __uint_as_float(v0 & 0xffff0000u) + __uint_as_float(v1 & 0xffff0000u)
            + __uint_as_float(v2 & 0xffff0000u) + __uint_as_float(v3 & 0xffff0000u);
    }
    for (; i < e; i++) {
        uint32_t s = esrc[i];
        uint32_t v = h2[(size_t)s * 64 + lane];
        a0 += __uint_as_float(v << 16);
        a1 += __uint_as_float(v & 0xffff0000u);
    }
    float rs = rsqrtf(fmaxf((float)(e - b), 1.f));
    out2[(size_t)node * 64 + lane] = make_float2(a0 * rs, a1 * rs);
}

extern "C" void kernel_launch(void* const* d_in, const int* in_sizes, int n_in,
                              void* d_out, int out_size, void* d_ws, size_t ws_size,
                              hipStream_t stream) {
    const float* x    = (const float*)d_in[0];
    const int*   snd  = (const int*)d_in[1];
    const int*   rcv  = (const int*)d_in[2];
    const float* W    = (const float*)d_in[4];
    const float* bias = (const float*)d_in[5];

    char* ws = (char*)d_ws;
    short* h       = (short*)(ws + OFF_H);
    int* sdeg      = (int*)(ws + OFF_SDEG);
    int* rdeg      = (int*)(ws + OFF_RDEG);
    int* rowp      = (int*)(ws + OFF_ROWP);
    int* bsum      = (int*)(ws + OFF_BSUM);
    int* bcur      = (int*)(ws + OFF_BCUR);
    uint32_t* ebuf = (uint32_t*)(ws + OFF_EBUF);

    hipMemsetAsync(ws + OFF_SDEG, 0, 2 * N_NODES * sizeof(int), stream);

    deg_kernel      <<<(N_EDGES + 255) / 256, 256, 0, stream>>>(snd, rcv, sdeg, rdeg);
    scan1_kernel    <<<196, 512, 0, stream>>>(rdeg, rowp, bsum);
    scan2_kernel    <<<1, 256, 0, stream>>>(bsum);
    scan3_kernel    <<<196, 512, 0, stream>>>(rowp, bsum, bcur);
    gemm_mfma_kernel<<<(N_NODES + 127) / 128, 256, 0, stream>>>(x, W, bias, sdeg, h);
    scatter1_kernel <<<S1_BLOCKS, 256, 0, stream>>>(snd, rcv, bcur, ebuf);
    scatter2_kernel <<<N_BUCKETS, 256, 0, stream>>>(rowp, ebuf);
    gather_kernel   <<<N_NODES / 4, 256, 0, stream>>>((const uint32_t*)h, rowp, ebuf, (float2*)d_out);
}

// Round 5
// 275.839 us; speedup vs baseline: 2.5494x; 1.3106x over previous
//
#include <hip/hip_runtime.h>
#include <hip/hip_bf16.h>
#include <stdint.h>

#define N_NODES 100000
#define N_EDGES 1600000
#define TILE 8192
#define NB 196                                 // 196 blocks/buckets: bucket = id>>9
#define BIN_BLOCKS ((N_EDGES + TILE - 1) / TILE)   // 196

// ---- workspace layout (bytes) ----
static const size_t OFF_H      = 0;            // h bf16: 25,600,000
static const size_t OFF_SSCALE = 25600000;     // float 400,000  (rsqrt(max(sdeg,1)))
static const size_t OFF_ROWP   = 26000000;     // int 400,004
static const size_t OFF_RHIST  = 26400016;     // int 1024 (196 used)
static const size_t OFF_SHIST  = 26401040;     // int 1024 (contiguous w/ RHIST for memset)
static const size_t OFF_RBASE  = 26402064;     // int 1024
static const size_t OFF_SBASE  = 26403088;     // int 1024
static const size_t OFF_RCUR   = 26404112;     // int 1024
static const size_t OFF_SCUR   = 26405136;     // int 1024
static const size_t OFF_EBUF   = 26406160;     // uint32 6,400,000
static const size_t OFF_SBUF   = 32806160;     // uint16 3,200,000 -> total ~36.0 MB

using short8 = __attribute__((ext_vector_type(8))) short;
using f32x4  = __attribute__((ext_vector_type(4))) float;

static __device__ __forceinline__ short f2bf(float f) {
    uint32_t u = __float_as_uint(f);
    uint32_t r = (u + 0x7fffu + ((u >> 16) & 1u)) >> 16;
    return (short)r;
}

// 1) coarse histograms (196 bins each for rcv>>9 and snd>>9), LDS-staged
__global__ __launch_bounds__(256) void hist196_kernel(const int* __restrict__ snd,
                                                      const int* __restrict__ rcv,
                                                      int* __restrict__ rhist,
                                                      int* __restrict__ shist) {
    __shared__ int hr[256], hs[256];
    int t = threadIdx.x;
    hr[t] = 0; hs[t] = 0;
    __syncthreads();
    int base = blockIdx.x * TILE;
    #pragma unroll
    for (int j = 0; j < 32; j++) {
        int idx = base + j * 256 + t;
        if (idx < N_EDGES) {
            atomicAdd(&hr[rcv[idx] >> 9], 1);
            atomicAdd(&hs[snd[idx] >> 9], 1);
        }
    }
    __syncthreads();
    if (t < NB) {
        if (hr[t]) atomicAdd(&rhist[t], hr[t]);
        if (hs[t]) atomicAdd(&shist[t], hs[t]);
    }
}

// 2) scan both 196-bucket histograms -> bases + working cursors
__global__ __launch_bounds__(256) void scanb_kernel(const int* __restrict__ rhist,
                                                    const int* __restrict__ shist,
                                                    int* __restrict__ rbase,
                                                    int* __restrict__ sbase,
                                                    int* __restrict__ rcur,
                                                    int* __restrict__ scur,
                                                    int* __restrict__ row_ptr) {
    __shared__ int s[256];
    int t = threadIdx.x;

    int v = (t < NB) ? rhist[t] : 0;
    s[t] = v;
    __syncthreads();
    #pragma unroll
    for (int off = 1; off < 256; off <<= 1) {
        int tv = (t >= off) ? s[t - off] : 0;
        __syncthreads();
        s[t] += tv;
        __syncthreads();
    }
    if (t < NB) { int e = s[t] - v; rbase[t] = e; rcur[t] = e; }
    __syncthreads();

    v = (t < NB) ? shist[t] : 0;
    s[t] = v;
    __syncthreads();
    #pragma unroll
    for (int off = 1; off < 256; off <<= 1) {
        int tv = (t >= off) ? s[t - off] : 0;
        __syncthreads();
        s[t] += tv;
        __syncthreads();
    }
    if (t < NB) { int e = s[t] - v; sbase[t] = e; scur[t] = e; }
    if (t == 0) row_ptr[N_NODES] = N_EDGES;
}

// 3) fused binning: r-channel packs (snd<<9|rcv&511) -> ebuf grouped by rcv>>9;
//    s-channel packs uint16(snd&511) -> sbuf grouped by snd>>9. All global
//    writes are LDS-staged contiguous bursts.
__global__ __launch_bounds__(256) void binr_kernel(const int* __restrict__ snd,
                                                   const int* __restrict__ rcv,
                                                   int* __restrict__ rcur,
                                                   int* __restrict__ scur,
                                                   uint32_t* __restrict__ ebuf,
                                                   uint16_t* __restrict__ sbuf) {
    __shared__ int hist[256];
    __shared__ int coff[256];
    __shared__ int ccur[256];
    __shared__ int gbase[256];
    __shared__ uint32_t stage[TILE];           // 32 KB (reused by s-channel as u16)

    const int t = threadIdx.x;
    const int base = blockIdx.x * TILE;

    uint32_t ss[32], rs[32];
    #pragma unroll
    for (int j = 0; j < 32; j++) {
        int idx = base + j * 256 + t;
        bool ok = idx < N_EDGES;
        ss[j] = ok ? (uint32_t)snd[idx] : 0u;
        rs[j] = ok ? (uint32_t)rcv[idx] : 0xffffffffu;
    }

    // ---------------- r-channel ----------------
    hist[t] = 0;
    __syncthreads();
    #pragma unroll
    for (int j = 0; j < 32; j++)
        if (rs[j] != 0xffffffffu) atomicAdd(&hist[rs[j] >> 9], 1);
    __syncthreads();

    int v = hist[t];
    ccur[t] = v;
    __syncthreads();
    #pragma unroll
    for (int off = 1; off < 256; off <<= 1) {
        int tv = (t >= off) ? ccur[t - off] : 0;
        __syncthreads();
        ccur[t] += tv;
        __syncthreads();
    }
    int excl = ccur[t] - v;
    coff[t] = excl;
    int gb = 0;
    if (v > 0) gb = atomicAdd(&rcur[t], v);
    gbase[t] = gb - excl;
    __syncthreads();
    ccur[t] = excl;
    __syncthreads();

    #pragma unroll
    for (int j = 0; j < 32; j++) {
        uint32_t r = rs[j];
        if (r != 0xffffffffu) {
            int pos = atomicAdd(&ccur[r >> 9], 1);
            stage[pos] = (ss[j] << 9) | (r & 511u);
        }
    }
    __syncthreads();

    int total = coff[255] + hist[255];
    for (int i = t; i < total; i += 256) {
        uint32_t pv = stage[i];
        int lo = 0;
        #pragma unroll
        for (int step = 128; step; step >>= 1)
            if (lo + step < 256 && coff[lo + step] <= i) lo += step;
        ebuf[gbase[lo] + i] = pv;
    }
    __syncthreads();

    // ---------------- s-channel ----------------
    hist[t] = 0;
    __syncthreads();
    #pragma unroll
    for (int j = 0; j < 32; j++)
        if (rs[j] != 0xffffffffu) atomicAdd(&hist[ss[j] >> 9], 1);
    __syncthreads();

    v = hist[t];
    ccur[t] = v;
    __syncthreads();
    #pragma unroll
    for (int off = 1; off < 256; off <<= 1) {
        int tv = (t >= off) ? ccur[t - off] : 0;
        __syncthreads();
        ccur[t] += tv;
        __syncthreads();
    }
    excl = ccur[t] - v;
    coff[t] = excl;
    gb = 0;
    if (v > 0) gb = atomicAdd(&scur[t], v);
    gbase[t] = gb - excl;
    __syncthreads();
    ccur[t] = excl;
    __syncthreads();

    uint16_t* stage16 = (uint16_t*)stage;
    #pragma unroll
    for (int j = 0; j < 32; j++) {
        if (rs[j] != 0xffffffffu) {
            int pos = atomicAdd(&ccur[ss[j] >> 9], 1);
            stage16[pos] = (uint16_t)(ss[j] & 511u);
        }
    }
    __syncthreads();

    total = coff[255] + hist[255];
    for (int i = t; i < total; i += 256) {
        uint16_t pv = stage16[i];
        int lo = 0;
        #pragma unroll
        for (int step = 128; step; step >>= 1)
            if (lo + step < 256 && coff[lo + step] <= i) lo += step;
        sbuf[gbase[lo] + i] = pv;
    }
}

// 4) per-bucket finalize: local rdeg hist -> row_ptr (coalesced write) + in-place
//    receiver-sort of senders; s-channel hist -> sscale (coalesced write).
__global__ __launch_bounds__(256) void bucket_kernel(const int* __restrict__ rbase,
                                                     const int* __restrict__ rhist,
                                                     const int* __restrict__ sbase,
                                                     const int* __restrict__ shist,
                                                     uint32_t* __restrict__ ebuf,
                                                     const uint16_t* __restrict__ sbuf,
                                                     int* __restrict__ row_ptr,
                                                     float* __restrict__ sscale) {
    __shared__ int hist_l[512];
    __shared__ int excl_l[512];
    __shared__ int cur_l[512];
    __shared__ int ps[256];
    __shared__ uint32_t inb[9216];    // 36 KB (bucket mean 8192, sigma ~90)
    __shared__ uint32_t perm[9216];   // 36 KB

    const int b = blockIdx.x;
    const int t = threadIdx.x;
    const int nbase = b << 9;
    const int base = rbase[b];
    const int size = rhist[b];

    hist_l[t] = 0; hist_l[t + 256] = 0;
    __syncthreads();

    for (int i = t; i < size; i += 256) {
        uint32_t v = ebuf[base + i];
        inb[i] = v;
        atomicAdd(&hist_l[v & 511u], 1);
    }
    __syncthreads();

    // 512-bin exclusive scan via 256 pair-sums
    int h0 = hist_l[2 * t], h1 = hist_l[2 * t + 1];
    int p = h0 + h1;
    ps[t] = p;
    __syncthreads();
    #pragma unroll
    for (int off = 1; off < 256; off <<= 1) {
        int tv = (t >= off) ? ps[t - off] : 0;
        __syncthreads();
        ps[t] += tv;
        __syncthreads();
    }
    int pe = ps[t] - p;
    excl_l[2 * t] = pe;
    excl_l[2 * t + 1] = pe + h0;
    cur_l[2 * t] = pe;
    cur_l[2 * t + 1] = pe + h0;
    __syncthreads();

    for (int i = t; i < 512; i += 256) {
        int n = nbase + i;
        if (n < N_NODES) row_ptr[n] = base + excl_l[i];
    }

    for (int i = t; i < size; i += 256) {
        uint32_t v = inb[i];
        int pos = atomicAdd(&cur_l[v & 511u], 1);
        perm[pos] = v >> 9;
    }
    __syncthreads();
    for (int i = t; i < size; i += 256)
        ebuf[base + i] = perm[i];

    // ---- s-channel: sender degree -> scale
    __syncthreads();
    hist_l[t] = 0; hist_l[t + 256] = 0;
    __syncthreads();
    const int sb = sbase[b];
    const int ssz = shist[b];
    for (int i = t; i < ssz; i += 256)
        atomicAdd(&hist_l[(int)sbuf[sb + i]], 1);
    __syncthreads();
    for (int i = t; i < 512; i += 256) {
        int n = nbase + i;
        if (n < N_NODES) sscale[n] = rsqrtf(fmaxf((float)hist_l[i], 1.f));
    }
}

// 5) MFMA GEMM: h[n][d] = bf16((x[n]·W[:,d] + bias[d]) * sscale[n])
__global__ __launch_bounds__(256) void gemm_mfma_kernel(const float* __restrict__ x,
                                                        const float* __restrict__ W,
                                                        const float* __restrict__ bias,
                                                        const float* __restrict__ sscale,
                                                        short* __restrict__ h) {
    __shared__ __align__(16) short Wl[32 * 64 * 8];
    __shared__ float bias_s[128];

    const int t = threadIdx.x;
    const int lane = t & 63;
    const int wv = t >> 6;
    const int quad = lane >> 4;
    const int mcol = lane & 15;

    #pragma unroll
    for (int i = 0; i < 8; i++) {
        int f = wv + 4 * i;
        int s = f >> 3;
        int c = f & 7;
        int krow = s * 32 + quad * 8;
        int ncol = c * 16 + mcol;
        short8 wf;
        #pragma unroll
        for (int j = 0; j < 8; j++)
            wf[j] = f2bf(W[(krow + j) * 128 + ncol]);
        *(short8*)&Wl[(f * 64 + lane) * 8] = wf;
    }
    if (t < 128) bias_s[t] = bias[t];

    const int node0 = blockIdx.x * 128 + wv * 32;
    short8 afrag[2][4];
    #pragma unroll
    for (int mf = 0; mf < 2; mf++) {
        int node = node0 + mf * 16 + mcol;
        bool ok = node < N_NODES;
        const float* xr = x + (size_t)(ok ? node : 0) * 128;
        #pragma unroll
        for (int s = 0; s < 4; s++) {
            int k0 = s * 32 + quad * 8;
            f32x4 v0 = ok ? *(const f32x4*)(xr + k0)     : f32x4{0.f,0.f,0.f,0.f};
            f32x4 v1 = ok ? *(const f32x4*)(xr + k0 + 4) : f32x4{0.f,0.f,0.f,0.f};
            short8 af;
            #pragma unroll
            for (int j = 0; j < 4; j++) {
                af[j]     = f2bf(v0[j]);
                af[4 + j] = f2bf(v1[j]);
            }
            afrag[mf][s] = af;
        }
    }

    __syncthreads();

    f32x4 acc[2][8];
    #pragma unroll
    for (int mf = 0; mf < 2; mf++)
        #pragma unroll
        for (int c = 0; c < 8; c++)
            acc[mf][c] = f32x4{0.f, 0.f, 0.f, 0.f};

    #pragma unroll
    for (int s = 0; s < 4; s++) {
        #pragma unroll
        for (int c = 0; c < 8; c++) {
            short8 bfrag = *(const short8*)&Wl[((s * 8 + c) * 64 + lane) * 8];
            acc[0][c] = __builtin_amdgcn_mfma_f32_16x16x32_bf16(afrag[0][s], bfrag, acc[0][c], 0, 0, 0);
            acc[1][c] = __builtin_amdgcn_mfma_f32_16x16x32_bf16(afrag[1][s], bfrag, acc[1][c], 0, 0, 0);
        }
    }

    float rsv[2][4];
    #pragma unroll
    for (int mf = 0; mf < 2; mf++)
        #pragma unroll
        for (int r = 0; r < 4; r++) {
            int nd = node0 + mf * 16 + quad * 4 + r;
            rsv[mf][r] = (nd < N_NODES) ? sscale[nd] : 1.f;
        }

    #pragma unroll
    for (int mf = 0; mf < 2; mf++)
        #pragma unroll
        for (int c = 0; c < 8; c++) {
            float bval = bias_s[c * 16 + mcol];
            #pragma unroll
            for (int r = 0; r < 4; r++) {
                int nd = node0 + mf * 16 + quad * 4 + r;
                if (nd < N_NODES)
                    h[(size_t)nd * 128 + c * 16 + mcol] =
                        f2bf((acc[mf][c][r] + bval) * rsv[mf][r]);
            }
        }
}

// 6) gather: one wave per node; degree from row_ptr; 4-wide edge unroll
__global__ __launch_bounds__(256) void gather_kernel(const uint32_t* __restrict__ h2,
                                                     const int* __restrict__ row_ptr,
                                                     const uint32_t* __restrict__ esrc,
                                                     float2* __restrict__ out2) {
    int node = blockIdx.x * 4 + (threadIdx.x >> 6);
    int lane = threadIdx.x & 63;
    int b = row_ptr[node];
    int e = row_ptr[node + 1];
    float a0 = 0.f, a1 = 0.f;
    int i = b;
    for (; i + 4 <= e; i += 4) {
        uint32_t s0 = esrc[i + 0], s1 = esrc[i + 1], s2 = esrc[i + 2], s3 = esrc[i + 3];
        uint32_t v0 = h2[(size_t)s0 * 64 + lane];
        uint32_t v1 = h2[(size_t)s1 * 64 + lane];
        uint32_t v2 = h2[(size_t)s2 * 64 + lane];
        uint32_t v3 = h2[(size_t)s3 * 64 + lane];
        a0 += __uint_as_float(v0 << 16) + __uint_as_float(v1 << 16)
            + __uint_as_float(v2 << 16) + __uint_as_float(v3 << 16);
        a1 += __uint_as_float(v0 & 0xffff0000u) + __uint_as_float(v1 & 0xffff0000u)
            + __uint_as_float(v2 & 0xffff0000u) + __uint_as_float(v3 & 0xffff0000u);
    }
    for (; i < e; i++) {
        uint32_t s = esrc[i];
        uint32_t v = h2[(size_t)s * 64 + lane];
        a0 += __uint_as_float(v << 16);
        a1 += __uint_as_float(v & 0xffff0000u);
    }
    float rs = rsqrtf(fmaxf((float)(e - b), 1.f));
    out2[(size_t)node * 64 + lane] = make_float2(a0 * rs, a1 * rs);
}

extern "C" void kernel_launch(void* const* d_in, const int* in_sizes, int n_in,
                              void* d_out, int out_size, void* d_ws, size_t ws_size,
                              hipStream_t stream) {
    const float* x    = (const float*)d_in[0];
    const int*   snd  = (const int*)d_in[1];
    const int*   rcv  = (const int*)d_in[2];
    const float* W    = (const float*)d_in[4];
    const float* bias = (const float*)d_in[5];

    char* ws = (char*)d_ws;
    short*    h      = (short*)(ws + OFF_H);
    float*    sscale = (float*)(ws + OFF_SSCALE);
    int*      rowp   = (int*)(ws + OFF_ROWP);
    int*      rhist  = (int*)(ws + OFF_RHIST);
    int*      shist  = (int*)(ws + OFF_SHIST);
    int*      rbase  = (int*)(ws + OFF_RBASE);
    int*      sbase  = (int*)(ws + OFF_SBASE);
    int*      rcur   = (int*)(ws + OFF_RCUR);
    int*      scur   = (int*)(ws + OFF_SCUR);
    uint32_t* ebuf   = (uint32_t*)(ws + OFF_EBUF);
    uint16_t* sbuf   = (uint16_t*)(ws + OFF_SBUF);

    hipMemsetAsync(ws + OFF_RHIST, 0, 2048, stream);   // rhist + shist

    hist196_kernel <<<BIN_BLOCKS, 256, 0, stream>>>(snd, rcv, rhist, shist);
    scanb_kernel   <<<1, 256, 0, stream>>>(rhist, shist, rbase, sbase, rcur, scur, rowp);
    binr_kernel    <<<BIN_BLOCKS, 256, 0, stream>>>(snd, rcv, rcur, scur, ebuf, sbuf);
    bucket_kernel  <<<NB, 256, 0, stream>>>(rbase, rhist, sbase, shist, ebuf, sbuf, rowp, sscale);
    gemm_mfma_kernel<<<(N_NODES + 127) / 128, 256, 0, stream>>>(x, W, bias, sscale, h);
    gather_kernel  <<<N_NODES / 4, 256, 0, stream>>>((const uint32_t*)h, rowp, ebuf, (float2*)d_out);
}

// Round 6
// 272.299 us; speedup vs baseline: 2.5826x; 1.0130x over previous
//
#include <hip/hip_runtime.h>
#include <hip/hip_bf16.h>
#include <stdint.h>

#define N_NODES 100000
#define N_EDGES 1600000
#define TILE 8192
#define NB 196                                 // 196 buckets: bucket = id>>9
#define BIN_BLOCKS ((N_EDGES + TILE - 1) / TILE)   // 196

// ---- workspace layout (bytes) ----
static const size_t OFF_H      = 0;            // h bf16: 25,600,000
static const size_t OFF_SSCALE = 25600000;     // float 400,000
static const size_t OFF_ROWP   = 26000000;     // int 400,004
static const size_t OFF_RHIST  = 26400016;     // int 1024 (196 used)
static const size_t OFF_SHIST  = 26401040;     // int 1024 (contiguous w/ RHIST for memset)
static const size_t OFF_RBASE  = 26402064;     // int 1024
static const size_t OFF_SBASE  = 26403088;     // int 1024
static const size_t OFF_RCUR   = 26404112;     // int 1024
static const size_t OFF_SCUR   = 26405136;     // int 1024
static const size_t OFF_WFRAG  = 26406160;     // short8 x 2048 = 32,768 (16B aligned)
static const size_t OFF_EBUF   = 26438928;     // uint32 6,400,000
static const size_t OFF_SBUF   = 32838928;     // uint16 3,200,000 -> total ~36.04 MB

using short8 = __attribute__((ext_vector_type(8))) short;
using f32x4  = __attribute__((ext_vector_type(4))) float;

static __device__ __forceinline__ short f2bf(float f) {
    uint32_t u = __float_as_uint(f);
    uint32_t r = (u + 0x7fffu + ((u >> 16) & 1u)) >> 16;
    return (short)r;
}

// 0) pre-swizzle W into bf16 MFMA B-fragments (one-time, 2048 threads)
//    slot = f*64+lane; f = s*8+c; B[k=quad*8+j][n=c*16+mcol]
__global__ __launch_bounds__(256) void prep_w_kernel(const float* __restrict__ W,
                                                     short8* __restrict__ wfrag) {
    int slot = blockIdx.x * 256 + threadIdx.x;   // 0..2047
    int f = slot >> 6, lane = slot & 63;
    int quad = lane >> 4, mcol = lane & 15;
    int s = f >> 3, c = f & 7;
    int krow = s * 32 + quad * 8;
    int ncol = c * 16 + mcol;
    short8 wf;
    #pragma unroll
    for (int j = 0; j < 8; j++)
        wf[j] = f2bf(W[(krow + j) * 128 + ncol]);
    wfrag[slot] = wf;
}

// 1) coarse histograms (196 bins each for rcv>>9 and snd>>9), LDS-staged
__global__ __launch_bounds__(256) void hist196_kernel(const int* __restrict__ snd,
                                                      const int* __restrict__ rcv,
                                                      int* __restrict__ rhist,
                                                      int* __restrict__ shist) {
    __shared__ int hr[256], hs[256];
    int t = threadIdx.x;
    hr[t] = 0; hs[t] = 0;
    __syncthreads();
    int base = blockIdx.x * TILE;
    #pragma unroll
    for (int j = 0; j < 32; j++) {
        int idx = base + j * 256 + t;
        if (idx < N_EDGES) {
            atomicAdd(&hr[rcv[idx] >> 9], 1);
            atomicAdd(&hs[snd[idx] >> 9], 1);
        }
    }
    __syncthreads();
    if (t < NB) {
        if (hr[t]) atomicAdd(&rhist[t], hr[t]);
        if (hs[t]) atomicAdd(&shist[t], hs[t]);
    }
}

// 2) scan both 196-bucket histograms -> bases + working cursors
__global__ __launch_bounds__(256) void scanb_kernel(const int* __restrict__ rhist,
                                                    const int* __restrict__ shist,
                                                    int* __restrict__ rbase,
                                                    int* __restrict__ sbase,
                                                    int* __restrict__ rcur,
                                                    int* __restrict__ scur,
                                                    int* __restrict__ row_ptr) {
    __shared__ int s[256];
    int t = threadIdx.x;

    int v = (t < NB) ? rhist[t] : 0;
    s[t] = v;
    __syncthreads();
    #pragma unroll
    for (int off = 1; off < 256; off <<= 1) {
        int tv = (t >= off) ? s[t - off] : 0;
        __syncthreads();
        s[t] += tv;
        __syncthreads();
    }
    if (t < NB) { int e = s[t] - v; rbase[t] = e; rcur[t] = e; }
    __syncthreads();

    v = (t < NB) ? shist[t] : 0;
    s[t] = v;
    __syncthreads();
    #pragma unroll
    for (int off = 1; off < 256; off <<= 1) {
        int tv = (t >= off) ? s[t - off] : 0;
        __syncthreads();
        s[t] += tv;
        __syncthreads();
    }
    if (t < NB) { int e = s[t] - v; sbase[t] = e; scur[t] = e; }
    if (t == 0) row_ptr[N_NODES] = N_EDGES;
}

// 3) fused binning: r-channel packs (snd<<9|rcv&511) -> ebuf grouped by rcv>>9;
//    s-channel packs uint16(snd&511) -> sbuf grouped by snd>>9.
__global__ __launch_bounds__(256) void binr_kernel(const int* __restrict__ snd,
                                                   const int* __restrict__ rcv,
                                                   int* __restrict__ rcur,
                                                   int* __restrict__ scur,
                                                   uint32_t* __restrict__ ebuf,
                                                   uint16_t* __restrict__ sbuf) {
    __shared__ int hist[256];
    __shared__ int coff[256];
    __shared__ int ccur[256];
    __shared__ int gbase[256];
    __shared__ uint32_t stage[TILE];           // 32 KB

    const int t = threadIdx.x;
    const int base = blockIdx.x * TILE;

    uint32_t ss[32], rs[32];
    #pragma unroll
    for (int j = 0; j < 32; j++) {
        int idx = base + j * 256 + t;
        bool ok = idx < N_EDGES;
        ss[j] = ok ? (uint32_t)snd[idx] : 0u;
        rs[j] = ok ? (uint32_t)rcv[idx] : 0xffffffffu;
    }

    // ---------------- r-channel ----------------
    hist[t] = 0;
    __syncthreads();
    #pragma unroll
    for (int j = 0; j < 32; j++)
        if (rs[j] != 0xffffffffu) atomicAdd(&hist[rs[j] >> 9], 1);
    __syncthreads();

    int v = hist[t];
    ccur[t] = v;
    __syncthreads();
    #pragma unroll
    for (int off = 1; off < 256; off <<= 1) {
        int tv = (t >= off) ? ccur[t - off] : 0;
        __syncthreads();
        ccur[t] += tv;
        __syncthreads();
    }
    int excl = ccur[t] - v;
    coff[t] = excl;
    int gb = 0;
    if (v > 0) gb = atomicAdd(&rcur[t], v);
    gbase[t] = gb - excl;
    __syncthreads();
    ccur[t] = excl;
    __syncthreads();

    #pragma unroll
    for (int j = 0; j < 32; j++) {
        uint32_t r = rs[j];
        if (r != 0xffffffffu) {
            int pos = atomicAdd(&ccur[r >> 9], 1);
            stage[pos] = (ss[j] << 9) | (r & 511u);
        }
    }
    __syncthreads();

    int total = coff[255] + hist[255];
    for (int i = t; i < total; i += 256) {
        uint32_t pv = stage[i];
        int lo = 0;
        #pragma unroll
        for (int step = 128; step; step >>= 1)
            if (lo + step < 256 && coff[lo + step] <= i) lo += step;
        ebuf[gbase[lo] + i] = pv;
    }
    __syncthreads();

    // ---------------- s-channel ----------------
    hist[t] = 0;
    __syncthreads();
    #pragma unroll
    for (int j = 0; j < 32; j++)
        if (rs[j] != 0xffffffffu) atomicAdd(&hist[ss[j] >> 9], 1);
    __syncthreads();

    v = hist[t];
    ccur[t] = v;
    __syncthreads();
    #pragma unroll
    for (int off = 1; off < 256; off <<= 1) {
        int tv = (t >= off) ? ccur[t - off] : 0;
        __syncthreads();
        ccur[t] += tv;
        __syncthreads();
    }
    excl = ccur[t] - v;
    coff[t] = excl;
    gb = 0;
    if (v > 0) gb = atomicAdd(&scur[t], v);
    gbase[t] = gb - excl;
    __syncthreads();
    ccur[t] = excl;
    __syncthreads();

    uint16_t* stage16 = (uint16_t*)stage;
    #pragma unroll
    for (int j = 0; j < 32; j++) {
        if (rs[j] != 0xffffffffu) {
            int pos = atomicAdd(&ccur[ss[j] >> 9], 1);
            stage16[pos] = (uint16_t)(ss[j] & 511u);
        }
    }
    __syncthreads();

    total = coff[255] + hist[255];
    for (int i = t; i < total; i += 256) {
        uint16_t pv = stage16[i];
        int lo = 0;
        #pragma unroll
        for (int step = 128; step; step >>= 1)
            if (lo + step < 256 && coff[lo + step] <= i) lo += step;
        sbuf[gbase[lo] + i] = pv;
    }
}

// 4) per-bucket finalize: row_ptr + receiver-sort of senders + sender scale
__global__ __launch_bounds__(256) void bucket_kernel(const int* __restrict__ rbase,
                                                     const int* __restrict__ rhist,
                                                     const int* __restrict__ sbase,
                                                     const int* __restrict__ shist,
                                                     uint32_t* __restrict__ ebuf,
                                                     const uint16_t* __restrict__ sbuf,
                                                     int* __restrict__ row_ptr,
                                                     float* __restrict__ sscale) {
    __shared__ int hist_l[512];
    __shared__ int excl_l[512];
    __shared__ int cur_l[512];
    __shared__ int ps[256];
    __shared__ uint32_t inb[9216];
    __shared__ uint32_t perm[9216];

    const int b = blockIdx.x;
    const int t = threadIdx.x;
    const int nbase = b << 9;
    const int base = rbase[b];
    const int size = rhist[b];

    hist_l[t] = 0; hist_l[t + 256] = 0;
    __syncthreads();

    for (int i = t; i < size; i += 256) {
        uint32_t v = ebuf[base + i];
        inb[i] = v;
        atomicAdd(&hist_l[v & 511u], 1);
    }
    __syncthreads();

    int h0 = hist_l[2 * t], h1 = hist_l[2 * t + 1];
    int p = h0 + h1;
    ps[t] = p;
    __syncthreads();
    #pragma unroll
    for (int off = 1; off < 256; off <<= 1) {
        int tv = (t >= off) ? ps[t - off] : 0;
        __syncthreads();
        ps[t] += tv;
        __syncthreads();
    }
    int pe = ps[t] - p;
    excl_l[2 * t] = pe;
    excl_l[2 * t + 1] = pe + h0;
    cur_l[2 * t] = pe;
    cur_l[2 * t + 1] = pe + h0;
    __syncthreads();

    for (int i = t; i < 512; i += 256) {
        int n = nbase + i;
        if (n < N_NODES) row_ptr[n] = base + excl_l[i];
    }

    for (int i = t; i < size; i += 256) {
        uint32_t v = inb[i];
        int pos = atomicAdd(&cur_l[v & 511u], 1);
        perm[pos] = v >> 9;
    }
    __syncthreads();
    for (int i = t; i < size; i += 256)
        ebuf[base + i] = perm[i];

    __syncthreads();
    hist_l[t] = 0; hist_l[t + 256] = 0;
    __syncthreads();
    const int sb = sbase[b];
    const int ssz = shist[b];
    for (int i = t; i < ssz; i += 256)
        atomicAdd(&hist_l[(int)sbuf[sb + i]], 1);
    __syncthreads();
    for (int i = t; i < 512; i += 256) {
        int n = nbase + i;
        if (n < N_NODES) sscale[n] = rsqrtf(fmaxf((float)hist_l[i], 1.f));
    }
}

// 5) MFMA GEMM v3: B-fragments read straight from global (L2-resident 32 KB),
//    no LDS, no barriers. h[n][d] = bf16((x[n]·W[:,d] + bias[d]) * sscale[n])
__global__ __launch_bounds__(256, 3) void gemm_mfma_kernel(const float* __restrict__ x,
                                                           const short8* __restrict__ wfrag,
                                                           const float* __restrict__ bias,
                                                           const float* __restrict__ sscale,
                                                           short* __restrict__ h) {
    const int t = threadIdx.x;
    const int lane = t & 63;
    const int wv = t >> 6;
    const int quad = lane >> 4;
    const int mcol = lane & 15;

    const int node0 = blockIdx.x * 128 + wv * 32;
    short8 afrag[2][4];
    #pragma unroll
    for (int mf = 0; mf < 2; mf++) {
        int node = node0 + mf * 16 + mcol;
        bool ok = node < N_NODES;
        const float* xr = x + (size_t)(ok ? node : 0) * 128;
        #pragma unroll
        for (int s = 0; s < 4; s++) {
            int k0 = s * 32 + quad * 8;
            f32x4 v0 = ok ? *(const f32x4*)(xr + k0)     : f32x4{0.f,0.f,0.f,0.f};
            f32x4 v1 = ok ? *(const f32x4*)(xr + k0 + 4) : f32x4{0.f,0.f,0.f,0.f};
            short8 af;
            #pragma unroll
            for (int j = 0; j < 4; j++) {
                af[j]     = f2bf(v0[j]);
                af[4 + j] = f2bf(v1[j]);
            }
            afrag[mf][s] = af;
        }
    }

    f32x4 acc[2][8];
    #pragma unroll
    for (int mf = 0; mf < 2; mf++)
        #pragma unroll
        for (int c = 0; c < 8; c++)
            acc[mf][c] = f32x4{0.f, 0.f, 0.f, 0.f};

    #pragma unroll
    for (int s = 0; s < 4; s++) {
        #pragma unroll
        for (int c = 0; c < 8; c++) {
            short8 bfrag = wfrag[(s * 8 + c) * 64 + lane];
            acc[0][c] = __builtin_amdgcn_mfma_f32_16x16x32_bf16(afrag[0][s], bfrag, acc[0][c], 0, 0, 0);
            acc[1][c] = __builtin_amdgcn_mfma_f32_16x16x32_bf16(afrag[1][s], bfrag, acc[1][c], 0, 0, 0);
        }
    }

    float rsv[2][4];
    #pragma unroll
    for (int mf = 0; mf < 2; mf++)
        #pragma unroll
        for (int r = 0; r < 4; r++) {
            int nd = node0 + mf * 16 + quad * 4 + r;
            rsv[mf][r] = (nd < N_NODES) ? sscale[nd] : 1.f;
        }

    #pragma unroll
    for (int mf = 0; mf < 2; mf++)
        #pragma unroll
        for (int c = 0; c < 8; c++) {
            float bval = bias[c * 16 + mcol];
            #pragma unroll
            for (int r = 0; r < 4; r++) {
                int nd = node0 + mf * 16 + quad * 4 + r;
                if (nd < N_NODES)
                    h[(size_t)nd * 128 + c * 16 + mcol] =
                        f2bf((acc[mf][c][r] + bval) * rsv[mf][r]);
            }
        }
}

// 6) gather v2: 2 nodes per wave (32 lanes x 4 dims via dwordx2), 4-deep unroll
//    -> 8 rows in flight per wave. Coalesced float4 out writes.
__global__ __launch_bounds__(256) void gather_kernel(const uint32_t* __restrict__ h2,
                                                     const int* __restrict__ row_ptr,
                                                     const uint32_t* __restrict__ esrc,
                                                     float4* __restrict__ out4) {
    int wv = threadIdx.x >> 6;
    int lane = threadIdx.x & 63;
    int half = lane >> 5;
    int ln = lane & 31;
    int node = blockIdx.x * 8 + wv * 2 + half;

    int b = row_ptr[node];
    int e = row_ptr[node + 1];
    float a0 = 0.f, a1 = 0.f, a2 = 0.f, a3 = 0.f;
    int i = b;
    for (; i + 4 <= e; i += 4) {
        uint32_t s0 = esrc[i + 0], s1 = esrc[i + 1], s2 = esrc[i + 2], s3 = esrc[i + 3];
        uint2 v0 = *(const uint2*)&h2[(size_t)s0 * 64 + ln * 2];
        uint2 v1 = *(const uint2*)&h2[(size_t)s1 * 64 + ln * 2];
        uint2 v2 = *(const uint2*)&h2[(size_t)s2 * 64 + ln * 2];
        uint2 v3 = *(const uint2*)&h2[(size_t)s3 * 64 + ln * 2];
        a0 += __uint_as_float(v0.x << 16) + __uint_as_float(v1.x << 16)
            + __uint_as_float(v2.x << 16) + __uint_as_float(v3.x << 16);
        a1 += __uint_as_float(v0.x & 0xffff0000u) + __uint_as_float(v1.x & 0xffff0000u)
            + __uint_as_float(v2.x & 0xffff0000u) + __uint_as_float(v3.x & 0xffff0000u);
        a2 += __uint_as_float(v0.y << 16) + __uint_as_float(v1.y << 16)
            + __uint_as_float(v2.y << 16) + __uint_as_float(v3.y << 16);
        a3 += __uint_as_float(v0.y & 0xffff0000u) + __uint_as_float(v1.y & 0xffff0000u)
            + __uint_as_float(v2.y & 0xffff0000u) + __uint_as_float(v3.y & 0xffff0000u);
    }
    for (; i < e; i++) {
        uint32_t s = esrc[i];
        uint2 v = *(const uint2*)&h2[(size_t)s * 64 + ln * 2];
        a0 += __uint_as_float(v.x << 16);
        a1 += __uint_as_float(v.x & 0xffff0000u);
        a2 += __uint_as_float(v.y << 16);
        a3 += __uint_as_float(v.y & 0xffff0000u);
    }
    float rs = rsqrtf(fmaxf((float)(e - b), 1.f));
    out4[(size_t)node * 32 + ln] = make_float4(a0 * rs, a1 * rs, a2 * rs, a3 * rs);
}

extern "C" void kernel_launch(void* const* d_in, const int* in_sizes, int n_in,
                              void* d_out, int out_size, void* d_ws, size_t ws_size,
                              hipStream_t stream) {
    const float* x    = (const float*)d_in[0];
    const int*   snd  = (const int*)d_in[1];
    const int*   rcv  = (const int*)d_in[2];
    const float* W    = (const float*)d_in[4];
    const float* bias = (const float*)d_in[5];

    char* ws = (char*)d_ws;
    short*    h      = (short*)(ws + OFF_H);
    float*    sscale = (float*)(ws + OFF_SSCALE);
    int*      rowp   = (int*)(ws + OFF_ROWP);
    int*      rhist  = (int*)(ws + OFF_RHIST);
    int*      shist  = (int*)(ws + OFF_SHIST);
    int*      rbase  = (int*)(ws + OFF_RBASE);
    int*      sbase  = (int*)(ws + OFF_SBASE);
    int*      rcur   = (int*)(ws + OFF_RCUR);
    int*      scur   = (int*)(ws + OFF_SCUR);
    short8*   wfrag  = (short8*)(ws + OFF_WFRAG);
    uint32_t* ebuf   = (uint32_t*)(ws + OFF_EBUF);
    uint16_t* sbuf   = (uint16_t*)(ws + OFF_SBUF);

    hipMemsetAsync(ws + OFF_RHIST, 0, 2048, stream);   // rhist + shist

    prep_w_kernel  <<<8, 256, 0, stream>>>(W, wfrag);
    hist196_kernel <<<BIN_BLOCKS, 256, 0, stream>>>(snd, rcv, rhist, shist);
    scanb_kernel   <<<1, 256, 0, stream>>>(rhist, shist, rbase, sbase, rcur, scur, rowp);
    binr_kernel    <<<BIN_BLOCKS, 256, 0, stream>>>(snd, rcv, rcur, scur, ebuf, sbuf);
    bucket_kernel  <<<NB, 256, 0, stream>>>(rbase, rhist, sbase, shist, ebuf, sbuf, rowp, sscale);
    gemm_mfma_kernel<<<(N_NODES + 127) / 128, 256, 0, stream>>>(x, wfrag, bias, sscale, h);
    gather_kernel  <<<N_NODES / 8, 256, 0, stream>>>((const uint32_t*)h, rowp, ebuf, (float4*)d_out);
}